// Round 4
// baseline (354.675 us; speedup 1.0000x reference)
//
#include <hip/hip_runtime.h>

#define B_  8
#define N_  16384
#define NC_ 64
#define C_  256

typedef __attribute__((ext_vector_type(8))) short bf16x8;
typedef __attribute__((ext_vector_type(4))) float f32x4;

// ws layout (bytes):
#define WS_GT   0           // GT[c][e] = sum_d Wc[e,d]*Wp[c,d], 256x256 f32
#define WS_BLOB 262144      // per batch: Vt 32KB | CfT(permuted frags) 32KB  (x8 = 512KB)
#define WS_S0   786432      // B*64 f32
#define WS_WFB  788480      // 256 f32  (Wc . bp)
#define WS_H    789504      // 256 f32  (bc . Wp[c,:])
#define WS_BB   790528      // 1 f32    (bc . bp)

__device__ __forceinline__ unsigned rne_bf16(float f) {
    unsigned u = __float_as_uint(f);
    return (u + 0x7fffu + ((u >> 16) & 1u)) >> 16;
}
__device__ __forceinline__ float bf2f(short s) {
    return __uint_as_float(((unsigned)(unsigned short)s) << 16);
}
__device__ __forceinline__ f32x4 mfma16(bf16x8 a, bf16x8 b, f32x4 c) {
    // D[r][c] = sum_k A[r][k]*B[c][k]; C/D: col=lane&15, row=(lane>>4)*4+reg
    return __builtin_amdgcn_mfma_f32_16x16x32_bf16(a, b, c, 0, 0, 0);
}

// ---------------- P1: GT = (Wc*Wp^T)^T, h, wfb, bb ----------------
__global__ __launch_bounds__(256) void k_p1(const float* __restrict__ Wp,
        const float* __restrict__ Wc, const float* __restrict__ bc,
        const float* __restrict__ bp, float* __restrict__ ws) {
    __shared__ float WpL[256];
    __shared__ float bpL[256];
    __shared__ float red[4];
    int c = blockIdx.x, t = threadIdx.x;
    WpL[t] = Wp[(size_t)c*C_ + t];
    bpL[t] = bp[t];
    float bcv = bc[t];
    __syncthreads();

    const float* wcr = Wc + (size_t)t*C_;
    float acc = 0.f;
    #pragma unroll 8
    for (int d = 0; d < C_; d += 4) {
        f32x4 wv = *(const f32x4*)(wcr + d);
        f32x4 wp = *(const f32x4*)(WpL + d);
        acc += wv[0]*wp[0] + wv[1]*wp[1] + wv[2]*wp[2] + wv[3]*wp[3];
    }
    ws[WS_GT/4 + c*C_ + t] = acc;

    float hp = bcv * WpL[t];
    #pragma unroll
    for (int m = 32; m; m >>= 1) hp += __shfl_xor(hp, m);
    if ((t & 63) == 0) red[t >> 6] = hp;
    __syncthreads();
    if (t == 0) ws[WS_H/4 + c] = red[0] + red[1] + red[2] + red[3];

    if (c == 0) {
        float aw = 0.f;
        #pragma unroll 8
        for (int d = 0; d < C_; d += 4) {
            f32x4 wv = *(const f32x4*)(wcr + d);
            f32x4 b4 = *(const f32x4*)(bpL + d);
            aw += wv[0]*b4[0] + wv[1]*b4[1] + wv[2]*b4[2] + wv[3]*b4[3];
        }
        ws[WS_WFB/4 + t] = aw;
        float pb = bcv * bpL[t];
        #pragma unroll
        for (int m = 32; m; m >>= 1) pb += __shfl_xor(pb, m);
        __syncthreads();
        if ((t & 63) == 0) red[t >> 6] = pb;
        __syncthreads();
        if (t == 0) ws[WS_BB/4] = red[0] + red[1] + red[2] + red[3];
    }
}

// ---------------- P2: Vt (bf16, plain rows), CfT (bf16, permuted frags), s0 ----------------
__global__ __launch_bounds__(256) void k_p2(const float* __restrict__ Cf,
        float* __restrict__ ws) {
    __shared__ float CfL[8][256];
    __shared__ float wfbL[256];
    int b = blockIdx.x >> 3, kg = blockIdx.x & 7;
    int t = threadIdx.x;
    const float* cfb = Cf + ((size_t)b*NC_ + kg*8)*C_;
    #pragma unroll
    for (int kk = 0; kk < 8; ++kk) CfL[kk][t] = cfb[kk*C_ + t];
    wfbL[t] = ws[WS_WFB/4 + t];
    float hv = ws[WS_H/4 + t];
    float bb = ws[WS_BB/4];
    __syncthreads();

    char* vtB  = (char*)ws + WS_BLOB + (size_t)b*65536;
    char* cftB = vtB + 32768;

    // CfT permuted-fragment layout: for feature c, centroid k:
    //   nf = ((c>>5)<<1)|((c>>2)&1), rho = ((c>>3)&3)*4 + (c&3)
    //   offset = nf*2048 + rho*128 + k*2
    {
        int nf  = ((t >> 5) << 1) | ((t >> 2) & 1);
        int rho = ((t >> 3) & 3) * 4 + (t & 3);
        unsigned base = (unsigned)(nf*2048 + rho*128);
        #pragma unroll
        for (int kk = 0; kk < 8; ++kk) {
            *(unsigned short*)(cftB + base + (kg*8 + kk)*2) =
                (unsigned short)rne_bf16(CfL[kk][t]);
        }
    }

    // Vt[k][c=t] = h[t] + sum_e CfL[k][e] * GT[t][e]
    float acc[8];
    #pragma unroll
    for (int kk = 0; kk < 8; ++kk) acc[kk] = hv;
    const float* gtr = ws + WS_GT/4 + (size_t)t*C_;
    #pragma unroll 4
    for (int e = 0; e < C_; e += 4) {
        f32x4 g4 = *(const f32x4*)(gtr + e);
        #pragma unroll
        for (int kk = 0; kk < 8; ++kk) {
            f32x4 c4 = *(const f32x4*)(&CfL[kk][e]);
            acc[kk] += g4[0]*c4[0] + g4[1]*c4[1] + g4[2]*c4[2] + g4[3]*c4[3];
        }
    }
    #pragma unroll
    for (int kk = 0; kk < 8; ++kk) {
        int row = kg*8 + kk;
        *(unsigned short*)(vtB + row*512 + t*2) = (unsigned short)rne_bf16(acc[kk]);
    }

    // s0[k] = Cf[k].wfb + bb
    int w = t >> 6, l = t & 63;
    #pragma unroll
    for (int kk = 2*w; kk < 2*w + 2; ++kk) {
        float s = 0.f;
        #pragma unroll
        for (int j = 0; j < 4; ++j) s += CfL[kk][l + 64*j] * wfbL[l + 64*j];
        #pragma unroll
        for (int m = 32; m; m >>= 1) s += __shfl_xor(s, m);
        if (l == 0) ws[WS_S0/4 + b*NC_ + kg*8 + kk] = s + bb;
    }
}

// ---------------- main: barrier-free, 256 thr (4 waves), 64 rows/block ----------------
__global__ __launch_bounds__(256, 4) void k_main(const float* __restrict__ P,
        const char* __restrict__ blob, const float* __restrict__ s0g,
        float* __restrict__ out) {
    __shared__ __align__(16) char wbAll[8192];   // 4 waves x 2KB weight round-trip

    int b    = blockIdx.x >> 8;           // 256 tiles per batch
    int tile = blockIdx.x & 255;
    int tid = threadIdx.x;
    int w   = tid >> 6;
    int l   = tid & 63;
    int l15 = l & 15;
    int g   = l >> 4;

    const char* blobV = blob + (size_t)b*65536;          // Vt rows [64][256] bf16
    const char* blobC = blobV + 32768;                   // CfT permuted frags

    int prow = tile*64 + w*16 + l15;
    const float* Prow = P + ((size_t)b*N_ + prow)*C_;

    // ---- s0 seed (issue first, L2-hot) ----
    f32x4 sacc[4];
    #pragma unroll
    for (int mf = 0; mf < 4; ++mf)
        sacc[mf] = *(const f32x4*)(s0g + b*NC_ + mf*16 + g*4);

    // ---- streaming score phase: 2-deep P prefetch, convert, MFMA from global frags ----
    bf16x8 phi[8], plo[8];
    f32x4 pA0 = *(const f32x4*)(Prow + g*8);
    f32x4 pA1 = *(const f32x4*)(Prow + g*8 + 4);
    f32x4 pB0 = *(const f32x4*)(Prow + g*8 + 32);
    f32x4 pB1 = *(const f32x4*)(Prow + g*8 + 36);

    #pragma unroll
    for (int kk = 0; kk < 8; ++kk) {
        // issue this kk's Vt fragment loads (coalesced 64B/row, L1/L2-hot)
        bf16x8 vh0 = *(const bf16x8*)(blobV + (0*16 + l15)*512 + kk*64 + g*16);
        bf16x8 vh1 = *(const bf16x8*)(blobV + (1*16 + l15)*512 + kk*64 + g*16);
        bf16x8 vh2 = *(const bf16x8*)(blobV + (2*16 + l15)*512 + kk*64 + g*16);
        bf16x8 vh3 = *(const bf16x8*)(blobV + (3*16 + l15)*512 + kk*64 + g*16);
        // convert current P pair to hi/lo bf16
        #pragma unroll
        for (int h = 0; h < 2; ++h) {
            f32x4 src = h ? pA1 : pA0;
            #pragma unroll
            for (int j = 0; j < 4; ++j) {
                float f  = src[j];
                unsigned hb = rne_bf16(f);
                float hf = __uint_as_float(hb << 16);
                unsigned lb = rne_bf16(f - hf);
                phi[kk][h*4 + j] = (short)hb;
                plo[kk][h*4 + j] = (short)lb;
            }
        }
        // rotate prefetch registers, issue kk+2
        pA0 = pB0; pA1 = pB1;
        if (kk < 6) {
            pB0 = *(const f32x4*)(Prow + g*8 + (kk+2)*32);
            pB1 = *(const f32x4*)(Prow + g*8 + (kk+2)*32 + 4);
        }
        sacc[0] = mfma16(vh0, phi[kk], sacc[0]);
        sacc[1] = mfma16(vh1, phi[kk], sacc[1]);
        sacc[2] = mfma16(vh2, phi[kk], sacc[2]);
        sacc[3] = mfma16(vh3, phi[kk], sacc[3]);
        sacc[0] = mfma16(vh0, plo[kk], sacc[0]);
        sacc[1] = mfma16(vh1, plo[kk], sacc[1]);
        sacc[2] = mfma16(vh2, plo[kk], sacc[2]);
        sacc[3] = mfma16(vh3, plo[kk], sacc[3]);
    }

    // ---- softmax over 64 centroids (lane holds 16; partners ^16, ^32) ----
    float mx = -3.0e38f;
    #pragma unroll
    for (int mf = 0; mf < 4; ++mf)
        #pragma unroll
        for (int r = 0; r < 4; ++r) mx = fmaxf(mx, sacc[mf][r]);
    mx = fmaxf(mx, __shfl_xor(mx, 16));
    mx = fmaxf(mx, __shfl_xor(mx, 32));
    float sum = 0.f;
    #pragma unroll
    for (int mf = 0; mf < 4; ++mf)
        #pragma unroll
        for (int r = 0; r < 4; ++r) {
            float e = __expf(sacc[mf][r] - mx);
            sacc[mf][r] = e; sum += e;
        }
    sum += __shfl_xor(sum, 16);
    sum += __shfl_xor(sum, 32);
    float inv = 1.0f / sum;

    // ---- weights -> per-wave swizzled LDS -> B-frag layout ----
    char* wb = wbAll + w*2048;   // [point 16][k 64] bf16, swz ^((row&7)<<4)
    #pragma unroll
    for (int mf = 0; mf < 4; ++mf) {
        unsigned w01 = rne_bf16(sacc[mf][0]*inv) | (rne_bf16(sacc[mf][1]*inv) << 16);
        unsigned w23 = rne_bf16(sacc[mf][2]*inv) | (rne_bf16(sacc[mf][3]*inv) << 16);
        unsigned off = ((unsigned)(l15*128 + mf*32 + g*8)) ^ ((unsigned)(l15 & 7) << 4);
        uint2 v; v.x = w01; v.y = w23;
        *(uint2*)(wb + off) = v;
    }
    unsigned woff0 = ((unsigned)(l15*128 +  0 + g*16)) ^ ((unsigned)(l15 & 7) << 4);
    unsigned woff1 = ((unsigned)(l15*128 + 64 + g*16)) ^ ((unsigned)(l15 & 7) << 4);
    bf16x8 wf0 = *(const bf16x8*)(wb + woff0);
    bf16x8 wf1 = *(const bf16x8*)(wb + woff1);

    // ---- PV per output-fragment, fused residual (from phi/plo regs) + store ----
    size_t rowbase = ((size_t)b*N_ + prow) * C_;
    #pragma unroll
    for (int nf = 0; nf < 16; ++nf) {
        const char* cbase = blobC + nf*2048 + l15*128 + g*16;
        bf16x8 cf0 = *(const bf16x8*)(cbase);
        bf16x8 cf1 = *(const bf16x8*)(cbase + 64);
        f32x4 o = {0.f, 0.f, 0.f, 0.f};
        o = mfma16(cf0, wf0, o);
        o = mfma16(cf1, wf1, o);
        int kf = nf >> 1, e0 = (nf & 1) * 4;
        f32x4 res;
        #pragma unroll
        for (int r = 0; r < 4; ++r)
            res[r] = bf2f(phi[kf][e0 + r]) + bf2f(plo[kf][e0 + r]) + o[r];
        *(f32x4*)(out + rowbase + (nf >> 1)*32 + (nf & 1)*4 + g*8) = res;
    }
}

extern "C" void kernel_launch(void* const* d_in, const int* in_sizes, int n_in,
                              void* d_out, int out_size, void* d_ws, size_t ws_size,
                              hipStream_t stream) {
    const float* P  = (const float*)d_in[0];
    const float* Cf = (const float*)d_in[1];
    const float* Wp = (const float*)d_in[2];
    const float* bp = (const float*)d_in[3];
    const float* Wc = (const float*)d_in[4];
    const float* bc = (const float*)d_in[5];
    float* out = (float*)d_out;
    float* ws  = (float*)d_ws;

    k_p1<<<256, 256, 0, stream>>>(Wp, Wc, bc, bp, ws);
    k_p2<<<64, 256, 0, stream>>>(Cf, ws);
    k_main<<<B_*(N_/64), 256, 0, stream>>>(P, (const char*)d_ws + WS_BLOB,
                                           ws + WS_S0/4, out);
}

// Round 5
// 321.300 us; speedup vs baseline: 1.1039x; 1.1039x over previous
//
#include <hip/hip_runtime.h>

#define B_  8
#define N_  16384
#define NC_ 64
#define C_  256

typedef __attribute__((ext_vector_type(8))) short bf16x8;
typedef __attribute__((ext_vector_type(4))) float f32x4;

// ws layout (bytes):
#define WS_GT   0           // GT[c][e] = sum_d Wc[e,d]*Wp[c,d], 256x256 f32
#define WS_BLOB 262144      // per batch: Vt 32KB | CfT 32KB  (x8 = 512KB)
#define WS_S0   786432      // B*64 f32
#define WS_WFB  788480      // 256 f32  (Wc . bp)
#define WS_H    789504      // 256 f32  (bc . Wp[c,:])
#define WS_BB   790528      // 1 f32    (bc . bp)

__device__ __forceinline__ unsigned rne_bf16(float f) {
    unsigned u = __float_as_uint(f);
    return (u + 0x7fffu + ((u >> 16) & 1u)) >> 16;
}
__device__ __forceinline__ f32x4 mfma16(bf16x8 a, bf16x8 b, f32x4 c) {
    // D[r][c] = sum_k A[r][k]*B[c][k]; C/D: col=lane&15, row=(lane>>4)*4+reg
    return __builtin_amdgcn_mfma_f32_16x16x32_bf16(a, b, c, 0, 0, 0);
}

// ---------------- P1: GT = (Wc*Wp^T)^T, h, wfb, bb ----------------
__global__ __launch_bounds__(256) void k_p1(const float* __restrict__ Wp,
        const float* __restrict__ Wc, const float* __restrict__ bc,
        const float* __restrict__ bp, float* __restrict__ ws) {
    __shared__ float WpL[256];
    __shared__ float bpL[256];
    __shared__ float red[4];
    int c = blockIdx.x, t = threadIdx.x;
    WpL[t] = Wp[(size_t)c*C_ + t];
    bpL[t] = bp[t];
    float bcv = bc[t];
    __syncthreads();

    const float* wcr = Wc + (size_t)t*C_;
    float acc = 0.f;
    #pragma unroll 8
    for (int d = 0; d < C_; d += 4) {
        f32x4 wv = *(const f32x4*)(wcr + d);
        f32x4 wp = *(const f32x4*)(WpL + d);
        acc += wv[0]*wp[0] + wv[1]*wp[1] + wv[2]*wp[2] + wv[3]*wp[3];
    }
    ws[WS_GT/4 + c*C_ + t] = acc;

    float hp = bcv * WpL[t];
    #pragma unroll
    for (int m = 32; m; m >>= 1) hp += __shfl_xor(hp, m);
    if ((t & 63) == 0) red[t >> 6] = hp;
    __syncthreads();
    if (t == 0) ws[WS_H/4 + c] = red[0] + red[1] + red[2] + red[3];

    if (c == 0) {
        float aw = 0.f;
        #pragma unroll 8
        for (int d = 0; d < C_; d += 4) {
            f32x4 wv = *(const f32x4*)(wcr + d);
            f32x4 b4 = *(const f32x4*)(bpL + d);
            aw += wv[0]*b4[0] + wv[1]*b4[1] + wv[2]*b4[2] + wv[3]*b4[3];
        }
        ws[WS_WFB/4 + t] = aw;
        float pb = bcv * bpL[t];
        #pragma unroll
        for (int m = 32; m; m >>= 1) pb += __shfl_xor(pb, m);
        __syncthreads();
        if ((t & 63) == 0) red[t >> 6] = pb;
        __syncthreads();
        if (t == 0) ws[WS_BB/4] = red[0] + red[1] + red[2] + red[3];
    }
}

// ---------------- P2: Vt (bf16 rows), CfT (bf16 [feature][centroid]), s0 ----------------
__global__ __launch_bounds__(256) void k_p2(const float* __restrict__ Cf,
        float* __restrict__ ws) {
    __shared__ float CfL[8][256];
    __shared__ float wfbL[256];
    int b = blockIdx.x >> 3, kg = blockIdx.x & 7;
    int t = threadIdx.x;
    const float* cfb = Cf + ((size_t)b*NC_ + kg*8)*C_;
    #pragma unroll
    for (int kk = 0; kk < 8; ++kk) CfL[kk][t] = cfb[kk*C_ + t];
    wfbL[t] = ws[WS_WFB/4 + t];
    float hv = ws[WS_H/4 + t];
    float bb = ws[WS_BB/4];
    __syncthreads();

    char* vtB  = (char*)ws + WS_BLOB + (size_t)b*65536;
    char* cftB = vtB + 32768;

    // CfT: [feature c][centroid k] bf16, row stride 128B, plain (global reads need no swizzle)
    #pragma unroll
    for (int kk = 0; kk < 8; ++kk) {
        *(unsigned short*)(cftB + t*128 + (kg*8 + kk)*2) =
            (unsigned short)rne_bf16(CfL[kk][t]);
    }

    // Vt[k][c=t] = h[t] + sum_e CfL[k][e] * GT[t][e]
    float acc[8];
    #pragma unroll
    for (int kk = 0; kk < 8; ++kk) acc[kk] = hv;
    const float* gtr = ws + WS_GT/4 + (size_t)t*C_;
    #pragma unroll 4
    for (int e = 0; e < C_; e += 4) {
        f32x4 g4 = *(const f32x4*)(gtr + e);
        #pragma unroll
        for (int kk = 0; kk < 8; ++kk) {
            f32x4 c4 = *(const f32x4*)(&CfL[kk][e]);
            acc[kk] += g4[0]*c4[0] + g4[1]*c4[1] + g4[2]*c4[2] + g4[3]*c4[3];
        }
    }
    #pragma unroll
    for (int kk = 0; kk < 8; ++kk) {
        int row = kg*8 + kk;
        *(unsigned short*)(vtB + row*512 + t*2) = (unsigned short)rne_bf16(acc[kk]);
    }

    // s0[k] = Cf[k].wfb + bb
    int w = t >> 6, l = t & 63;
    #pragma unroll
    for (int kk = 2*w; kk < 2*w + 2; ++kk) {
        float s = 0.f;
        #pragma unroll
        for (int j = 0; j < 4; ++j) s += CfL[kk][l + 64*j] * wfbL[l + 64*j];
        #pragma unroll
        for (int m = 32; m; m >>= 1) s += __shfl_xor(s, m);
        if (l == 0) ws[WS_S0/4 + b*NC_ + kg*8 + kk] = s + bb;
    }
}

// ---------------- main: barrier-free, 256 thr (4 waves), 64 rows/block ----------------
__global__ __launch_bounds__(256, 4) void k_main(const float* __restrict__ P,
        const char* __restrict__ blob, const float* __restrict__ s0g,
        float* __restrict__ out) {
    __shared__ __align__(16) char wbAll[8192];   // 4 waves x 2KB weight round-trip

    int b    = blockIdx.x >> 8;           // 256 tiles per batch
    int tile = blockIdx.x & 255;
    int tid = threadIdx.x;
    int w   = tid >> 6;
    int l   = tid & 63;
    int l15 = l & 15;
    int g   = l >> 4;

    const char* blobV = blob + (size_t)b*65536;   // Vt [64 centroids][256 feats] bf16
    const char* blobC = blobV + 32768;            // CfT [256 feats][64 centroids] bf16

    int prow = tile*64 + w*16 + l15;
    size_t rowbase = ((size_t)b*N_ + prow) * C_;
    const float* Prow = P + rowbase + g*8;

    // ---- issue ALL 16 P loads upfront (256B/lane in flight -> MLP for HBM) ----
    f32x4 pf[16];
    #pragma unroll
    for (int kk = 0; kk < 8; ++kk) {
        pf[2*kk]   = *(const f32x4*)(Prow + kk*32);
        pf[2*kk+1] = *(const f32x4*)(Prow + kk*32 + 4);
    }
    // ---- s0 seed (L2-hot) ----
    f32x4 sacc[4];
    #pragma unroll
    for (int mf = 0; mf < 4; ++mf)
        sacc[mf] = *(const f32x4*)(s0g + b*NC_ + mf*16 + g*4);

    // ---- score phase: convert-as-consumed, MFMA against global Vt fragments ----
    #pragma unroll
    for (int kk = 0; kk < 8; ++kk) {
        bf16x8 vh0 = *(const bf16x8*)(blobV + (0*16 + l15)*512 + kk*64 + g*16);
        bf16x8 vh1 = *(const bf16x8*)(blobV + (1*16 + l15)*512 + kk*64 + g*16);
        bf16x8 vh2 = *(const bf16x8*)(blobV + (2*16 + l15)*512 + kk*64 + g*16);
        bf16x8 vh3 = *(const bf16x8*)(blobV + (3*16 + l15)*512 + kk*64 + g*16);
        bf16x8 phi, plo;
        #pragma unroll
        for (int h = 0; h < 2; ++h) {
            f32x4 src = h ? pf[2*kk+1] : pf[2*kk];
            #pragma unroll
            for (int j = 0; j < 4; ++j) {
                float f  = src[j];
                unsigned hb = rne_bf16(f);
                float hf = __uint_as_float(hb << 16);
                unsigned lb = rne_bf16(f - hf);
                phi[h*4 + j] = (short)hb;
                plo[h*4 + j] = (short)lb;
            }
        }
        sacc[0] = mfma16(vh0, phi, sacc[0]);
        sacc[1] = mfma16(vh1, phi, sacc[1]);
        sacc[2] = mfma16(vh2, phi, sacc[2]);
        sacc[3] = mfma16(vh3, phi, sacc[3]);
        sacc[0] = mfma16(vh0, plo, sacc[0]);
        sacc[1] = mfma16(vh1, plo, sacc[1]);
        sacc[2] = mfma16(vh2, plo, sacc[2]);
        sacc[3] = mfma16(vh3, plo, sacc[3]);
    }

    // ---- softmax over 64 centroids (lane holds 16; partners ^16, ^32) ----
    float mx = -3.0e38f;
    #pragma unroll
    for (int mf = 0; mf < 4; ++mf)
        #pragma unroll
        for (int r = 0; r < 4; ++r) mx = fmaxf(mx, sacc[mf][r]);
    mx = fmaxf(mx, __shfl_xor(mx, 16));
    mx = fmaxf(mx, __shfl_xor(mx, 32));
    float sum = 0.f;
    #pragma unroll
    for (int mf = 0; mf < 4; ++mf)
        #pragma unroll
        for (int r = 0; r < 4; ++r) {
            float e = __expf(sacc[mf][r] - mx);
            sacc[mf][r] = e; sum += e;
        }
    sum += __shfl_xor(sum, 16);
    sum += __shfl_xor(sum, 32);
    float inv = 1.0f / sum;

    // ---- weights -> per-wave swizzled LDS -> B-frag layout (wave-local, no barrier) ----
    char* wb = wbAll + w*2048;   // [point 16][k 64] bf16, swz ^((row&7)<<4)
    #pragma unroll
    for (int mf = 0; mf < 4; ++mf) {
        unsigned w01 = rne_bf16(sacc[mf][0]*inv) | (rne_bf16(sacc[mf][1]*inv) << 16);
        unsigned w23 = rne_bf16(sacc[mf][2]*inv) | (rne_bf16(sacc[mf][3]*inv) << 16);
        unsigned off = ((unsigned)(l15*128 + mf*32 + g*8)) ^ ((unsigned)(l15 & 7) << 4);
        uint2 v; v.x = w01; v.y = w23;
        *(uint2*)(wb + off) = v;
    }
    unsigned woff0 = ((unsigned)(l15*128 +  0 + g*16)) ^ ((unsigned)(l15 & 7) << 4);
    unsigned woff1 = ((unsigned)(l15*128 + 64 + g*16)) ^ ((unsigned)(l15 & 7) << 4);
    bf16x8 wf0 = *(const bf16x8*)(wb + woff0);
    bf16x8 wf1 = *(const bf16x8*)(wb + woff1);

    // ---- PV + residual (P re-read, L1/L2-hot) + contiguous 64B/row stores ----
    #pragma unroll
    for (int nf = 0; nf < 16; ++nf) {
        const char* cbase = blobC + (nf*16 + l15)*128 + g*16;
        bf16x8 cf0 = *(const bf16x8*)(cbase);
        bf16x8 cf1 = *(const bf16x8*)(cbase + 64);
        f32x4 pr = *(const f32x4*)(P + rowbase + nf*16 + g*4);
        f32x4 o = {0.f, 0.f, 0.f, 0.f};
        o = mfma16(cf0, wf0, o);
        o = mfma16(cf1, wf1, o);
        f32x4 res = {pr[0]+o[0], pr[1]+o[1], pr[2]+o[2], pr[3]+o[3]};
        *(f32x4*)(out + rowbase + nf*16 + g*4) = res;
    }
}

extern "C" void kernel_launch(void* const* d_in, const int* in_sizes, int n_in,
                              void* d_out, int out_size, void* d_ws, size_t ws_size,
                              hipStream_t stream) {
    const float* P  = (const float*)d_in[0];
    const float* Cf = (const float*)d_in[1];
    const float* Wp = (const float*)d_in[2];
    const float* bp = (const float*)d_in[3];
    const float* Wc = (const float*)d_in[4];
    const float* bc = (const float*)d_in[5];
    float* out = (float*)d_out;
    float* ws  = (float*)d_ws;

    k_p1<<<256, 256, 0, stream>>>(Wp, Wc, bc, bp, ws);
    k_p2<<<64, 256, 0, stream>>>(Cf, ws);
    k_main<<<B_*(N_/64), 256, 0, stream>>>(P, (const char*)d_ws + WS_BLOB,
                                           ws + WS_S0/4, out);
}